// Round 5
// baseline (404.696 us; speedup 1.0000x reference)
//
#include <hip/hip_runtime.h>

#define NN   8192
#define DIN  512
#define H1   32
#define H2   16
#define NE   262144
#define EPSV 1e-32f

// ---------------- k1: XW0 = X @ W0   [NN x H1] ----------------
__global__ __launch_bounds__(256) void k_xw0(const float* __restrict__ X,
                                             const float* __restrict__ W0,
                                             float* __restrict__ XW0) {
    int t = blockIdx.x * 256 + threadIdx.x;
    int r = t >> 5, c = t & 31;
    const float4* Xr = reinterpret_cast<const float4*>(X + (size_t)r * DIN);
    float acc = 0.f;
#pragma unroll 8
    for (int k4 = 0; k4 < DIN / 4; ++k4) {
        float4 x = Xr[k4];
        int k = k4 * 4;
        acc = fmaf(x.x, W0[(k + 0) * H1 + c], acc);
        acc = fmaf(x.y, W0[(k + 1) * H1 + c], acc);
        acc = fmaf(x.z, W0[(k + 2) * H1 + c], acc);
        acc = fmaf(x.w, W0[(k + 3) * H1 + c], acc);
    }
    XW0[t] = acc;
}

// ---------------- k2: hacc += scatter(edge_val * XW0[col]) ----------------
// 32 lanes per edge; edge scalars broadcast; XW0 row 128B contiguous (L2);
// low-contention device atomics (faster end-to-end than CSR build, round-2 A/B).
__global__ __launch_bounds__(256) void k_spmm1(const int* __restrict__ er,
                                               const int* __restrict__ ec,
                                               const float* __restrict__ ev,
                                               const float* __restrict__ XW0,
                                               float* __restrict__ hacc) {
    int t = blockIdx.x * 256 + threadIdx.x;
    int e = t >> 5, c = t & 31;
    int row = er[e], col = ec[e];
    float v = ev[e];
    atomicAdd(&hacc[row * H1 + c], v * XW0[col * H1 + c]);
}

// ---------------- k3: HW1 = relu(hacc) @ W1   [NN x H2] ----------------
__global__ __launch_bounds__(256) void k_hw1(const float* __restrict__ hacc,
                                             const float* __restrict__ W1,
                                             float* __restrict__ HW1) {
    int t = blockIdx.x * 256 + threadIdx.x;
    int r = t >> 4, c = t & 15;
    const float* hr = hacc + r * H1;
    float acc = 0.f;
#pragma unroll
    for (int k = 0; k < H1; ++k)
        acc = fmaf(fmaxf(hr[k], 0.f), W1[k * H2 + c], acc);
    HW1[t] = acc;
}

// ---------------- k4: mean += scatter(edge_val * HW1[col]) ----------------
__global__ __launch_bounds__(256) void k_spmm2(const int* __restrict__ er,
                                               const int* __restrict__ ec,
                                               const float* __restrict__ ev,
                                               const float* __restrict__ HW1,
                                               float* __restrict__ mean) {
    int t = blockIdx.x * 256 + threadIdx.x;
    int e = t >> 4, c = t & 15;
    int row = er[e], col = ec[e];
    float v = ev[e];
    atomicAdd(&mean[row * H2 + c], v * HW1[col * H2 + c]);
}

// ---------------- k5: out = sigmoid(Z @ Z^T), Z = max(mean, EPS) ----------------
// 128x128 tile / 256 threads, thread tile 8i x 8j with j INTERLEAVED:
//   i = i0 + ty*8 + a,  j = j0 + tx + 16*b   (tx=tid&15, ty=tid>>4)
// zj reads: inter-lane row stride 1 -> granule stride 5 (odd, PAD=20) ->
//   spread over all 8 granule positions, 2-way = free (m136).
// zi reads: 16-lane broadcast per address; 4 distinct ty rows XOR-swizzled
//   across granules -> conflict-free. Stores: scalar nontemporal, 4x64B
//   segments per instruction (write-BW equivalent).
#define TI   128
#define PADJ 20

__device__ __forceinline__ float sigm(float x) {
    return __fdividef(1.0f, 1.0f + __expf(-x));
}

__global__ __launch_bounds__(256) void k_decode(const float* __restrict__ Zm,
                                                float* __restrict__ out) {
    __shared__ float zi[TI * 16];    // pitch 16, granule-XOR-swizzled
    __shared__ float zj[TI * PADJ];  // pitch 20
    const int i0 = blockIdx.y * TI, j0 = blockIdx.x * TI;
    const int tid = threadIdx.x;

#pragma unroll
    for (int l = 0; l < 2; ++l) {
        int t = tid + l * 256;          // 0..511
        int r = t >> 2, q = t & 3;      // row, float4-granule
        float4 a = *reinterpret_cast<const float4*>(Zm + (size_t)(i0 + r) * H2 + q * 4);
        float4 b = *reinterpret_cast<const float4*>(Zm + (size_t)(j0 + r) * H2 + q * 4);
        a.x = fmaxf(a.x, EPSV); a.y = fmaxf(a.y, EPSV);
        a.z = fmaxf(a.z, EPSV); a.w = fmaxf(a.w, EPSV);
        b.x = fmaxf(b.x, EPSV); b.y = fmaxf(b.y, EPSV);
        b.z = fmaxf(b.z, EPSV); b.w = fmaxf(b.w, EPSV);
        int qs = q ^ ((r >> 3) & 3);    // granule swizzle for zi
        *reinterpret_cast<float4*>(&zi[r * 16 + qs * 4]) = a;
        *reinterpret_cast<float4*>(&zj[r * PADJ + q * 4]) = b;
    }
    __syncthreads();

    const int tx = tid & 15, ty = tid >> 4;
    float acc[8][8] = {};
#pragma unroll
    for (int k4 = 0; k4 < 4; ++k4) {
        float4 ra[8], rb[8];
        const int qi = (k4 ^ (ty & 3)) * 4;   // un-swizzle: row>>3 == ty for rows ty*8+a
#pragma unroll
        for (int a = 0; a < 8; ++a)
            ra[a] = *reinterpret_cast<const float4*>(&zi[(ty * 8 + a) * 16 + qi]);
#pragma unroll
        for (int b = 0; b < 8; ++b)
            rb[b] = *reinterpret_cast<const float4*>(&zj[(tx + 16 * b) * PADJ + k4 * 4]);
#pragma unroll
        for (int a = 0; a < 8; ++a)
#pragma unroll
            for (int b = 0; b < 8; ++b) {
                acc[a][b] = fmaf(ra[a].x, rb[b].x, acc[a][b]);
                acc[a][b] = fmaf(ra[a].y, rb[b].y, acc[a][b]);
                acc[a][b] = fmaf(ra[a].z, rb[b].z, acc[a][b]);
                acc[a][b] = fmaf(ra[a].w, rb[b].w, acc[a][b]);
            }
    }

#pragma unroll
    for (int a = 0; a < 8; ++a) {
        size_t base = (size_t)(i0 + ty * 8 + a) * NN + j0 + tx;
#pragma unroll
        for (int b = 0; b < 8; ++b)
            __builtin_nontemporal_store(sigm(acc[a][b]), &out[base + 16 * b]);
    }
}

extern "C" void kernel_launch(void* const* d_in, const int* in_sizes, int n_in,
                              void* d_out, int out_size, void* d_ws, size_t ws_size,
                              hipStream_t stream) {
    const float* X  = (const float*)d_in[0];
    const int*   er = (const int*)d_in[1];
    const int*   ec = (const int*)d_in[2];
    const float* ev = (const float*)d_in[3];
    const float* W0 = (const float*)d_in[4];
    const float* W1 = (const float*)d_in[5];
    // d_in[6] = W2: dead in eval path.
    float* out = (float*)d_out;

    char* ws = (char*)d_ws;
    float* XW0  = (float*)(ws);                          // 1 MB
    float* hacc = (float*)(ws + (1 << 20));              // 1 MB
    float* mean = (float*)(ws + (2 << 20));              // 512 KB
    float* HW1  = (float*)(ws + (2 << 20) + (512 << 10));// 512 KB

    // zero the two atomic accumulators (contiguous)
    hipMemsetAsync(hacc, 0, (1 << 20) + (512 << 10), stream);

    k_xw0   <<<NN * H1 / 256, 256, 0, stream>>>(X, W0, XW0);
    k_spmm1 <<<NE * H1 / 256, 256, 0, stream>>>(er, ec, ev, XW0, hacc);
    k_hw1   <<<NN * H2 / 256, 256, 0, stream>>>(hacc, W1, HW1);
    k_spmm2 <<<NE * H2 / 256, 256, 0, stream>>>(er, ec, ev, HW1, mean);
    k_decode<<<dim3(NN / TI, NN / TI), 256, 0, stream>>>(mean, out);
}

// Round 6
// 375.240 us; speedup vs baseline: 1.0785x; 1.0785x over previous
//
#include <hip/hip_runtime.h>

#define NN   8192
#define DIN  512
#define H1   32
#define H2   16
#define NE   262144
#define EPSV 1e-32f

// ---------------- k1: XW0 = X @ W0   [NN x H1] ----------------
__global__ __launch_bounds__(256) void k_xw0(const float* __restrict__ X,
                                             const float* __restrict__ W0,
                                             float* __restrict__ XW0) {
    int t = blockIdx.x * 256 + threadIdx.x;
    int r = t >> 5, c = t & 31;
    const float4* Xr = reinterpret_cast<const float4*>(X + (size_t)r * DIN);
    float acc = 0.f;
#pragma unroll 8
    for (int k4 = 0; k4 < DIN / 4; ++k4) {
        float4 x = Xr[k4];
        int k = k4 * 4;
        acc = fmaf(x.x, W0[(k + 0) * H1 + c], acc);
        acc = fmaf(x.y, W0[(k + 1) * H1 + c], acc);
        acc = fmaf(x.z, W0[(k + 2) * H1 + c], acc);
        acc = fmaf(x.w, W0[(k + 3) * H1 + c], acc);
    }
    XW0[t] = acc;
}

// ---------------- k2: hacc += scatter(edge_val * XW0[col]) ----------------
__global__ __launch_bounds__(256) void k_spmm1(const int* __restrict__ er,
                                               const int* __restrict__ ec,
                                               const float* __restrict__ ev,
                                               const float* __restrict__ XW0,
                                               float* __restrict__ hacc) {
    int t = blockIdx.x * 256 + threadIdx.x;
    int e = t >> 5, c = t & 31;
    int row = er[e], col = ec[e];
    float v = ev[e];
    atomicAdd(&hacc[row * H1 + c], v * XW0[col * H1 + c]);
}

// ---------------- k3: HW1 = relu(hacc) @ W1   [NN x H2] ----------------
__global__ __launch_bounds__(256) void k_hw1(const float* __restrict__ hacc,
                                             const float* __restrict__ W1,
                                             float* __restrict__ HW1) {
    int t = blockIdx.x * 256 + threadIdx.x;
    int r = t >> 4, c = t & 15;
    const float* hr = hacc + r * H1;
    float acc = 0.f;
#pragma unroll
    for (int k = 0; k < H1; ++k)
        acc = fmaf(fmaxf(hr[k], 0.f), W1[k * H2 + c], acc);
    HW1[t] = acc;
}

// ---------------- k4: mean += scatter(edge_val * HW1[col]) ----------------
__global__ __launch_bounds__(256) void k_spmm2(const int* __restrict__ er,
                                               const int* __restrict__ ec,
                                               const float* __restrict__ ev,
                                               const float* __restrict__ HW1,
                                               float* __restrict__ mean) {
    int t = blockIdx.x * 256 + threadIdx.x;
    int e = t >> 4, c = t & 15;
    int row = er[e], col = ec[e];
    float v = ev[e];
    atomicAdd(&mean[row * H2 + c], v * HW1[col * H2 + c]);
}

// ---------------- k5: out = sigmoid(Z @ Z^T), Z = max(mean, EPS) ----------------
// Round-1 thread mapping (proven store path): i = i0+ty*8+a, j = j0+tx*8+b,
// contiguous float4 stores. Conflict fix moved into the zj LAYOUT:
//   zj pitch 32 words, granule q of row r stored at slot
//   p = (q ^ ((r>>3)&3)) | ((r>>3)&4).
// Reads (r = 8tx+b  =>  r>>3 = tx): p spans all 8 bank-quads for tx=0..7,
// tx vs tx+8 share a quad at different addrs -> 2-way = free (m136).
// Staging writes are 8 instrs/block -> their conflicts are negligible.
// zi: pitch 16, granule XOR by (r>>3)&3; reads are ty-broadcast, conflict-free.
#define TI 128

__device__ __forceinline__ float sigm(float x) {
    return __fdividef(1.0f, 1.0f + __expf(-x));
}

__global__ __launch_bounds__(256) void k_decode(const float* __restrict__ Zm,
                                                float* __restrict__ out) {
    __shared__ float zi[TI * 16];    // pitch 16, granule-XOR
    __shared__ float zj[TI * 32];    // pitch 32, 8-slot XOR placement
    const int i0 = blockIdx.y * TI, j0 = blockIdx.x * TI;
    const int tid = threadIdx.x;

#pragma unroll
    for (int l = 0; l < 2; ++l) {
        int t = tid + l * 256;          // 0..511
        int r = t >> 2, q = t & 3;      // row, float4-granule
        float4 a = *reinterpret_cast<const float4*>(Zm + (size_t)(i0 + r) * H2 + q * 4);
        float4 b = *reinterpret_cast<const float4*>(Zm + (size_t)(j0 + r) * H2 + q * 4);
        a.x = fmaxf(a.x, EPSV); a.y = fmaxf(a.y, EPSV);
        a.z = fmaxf(a.z, EPSV); a.w = fmaxf(a.w, EPSV);
        b.x = fmaxf(b.x, EPSV); b.y = fmaxf(b.y, EPSV);
        b.z = fmaxf(b.z, EPSV); b.w = fmaxf(b.w, EPSV);
        int g  = (r >> 3);              // 0..15
        int qs = q ^ (g & 3);                       // zi granule swizzle
        int p  = (q ^ (g & 3)) | (g & 4);           // zj slot placement
        *reinterpret_cast<float4*>(&zi[r * 16 + qs * 4]) = a;
        *reinterpret_cast<float4*>(&zj[r * 32 + p  * 4]) = b;
    }
    __syncthreads();

    const int tx = tid & 15, ty = tid >> 4;
    float acc[8][8] = {};
#pragma unroll
    for (int k4 = 0; k4 < 4; ++k4) {
        float4 ra[8], rb[8];
        const int qi = (k4 ^ (ty & 3)) * 4;              // zi un-swizzle (r>>3 == ty)
        const int pj = ((k4 ^ (tx & 3)) | (tx & 4)) * 4; // zj slot (r>>3 == tx)
#pragma unroll
        for (int a = 0; a < 8; ++a)
            ra[a] = *reinterpret_cast<const float4*>(&zi[(ty * 8 + a) * 16 + qi]);
#pragma unroll
        for (int b = 0; b < 8; ++b)
            rb[b] = *reinterpret_cast<const float4*>(&zj[(tx * 8 + b) * 32 + pj]);
#pragma unroll
        for (int a = 0; a < 8; ++a)
#pragma unroll
            for (int b = 0; b < 8; ++b) {
                acc[a][b] = fmaf(ra[a].x, rb[b].x, acc[a][b]);
                acc[a][b] = fmaf(ra[a].y, rb[b].y, acc[a][b]);
                acc[a][b] = fmaf(ra[a].z, rb[b].z, acc[a][b]);
                acc[a][b] = fmaf(ra[a].w, rb[b].w, acc[a][b]);
            }
    }

#pragma unroll
    for (int a = 0; a < 8; ++a) {
        size_t rowbase = (size_t)(i0 + ty * 8 + a) * NN + j0 + tx * 8;
#pragma unroll
        for (int b4 = 0; b4 < 8; b4 += 4) {
            float4 o;
            o.x = sigm(acc[a][b4 + 0]);
            o.y = sigm(acc[a][b4 + 1]);
            o.z = sigm(acc[a][b4 + 2]);
            o.w = sigm(acc[a][b4 + 3]);
            *reinterpret_cast<float4*>(out + rowbase + b4) = o;
        }
    }
}

extern "C" void kernel_launch(void* const* d_in, const int* in_sizes, int n_in,
                              void* d_out, int out_size, void* d_ws, size_t ws_size,
                              hipStream_t stream) {
    const float* X  = (const float*)d_in[0];
    const int*   er = (const int*)d_in[1];
    const int*   ec = (const int*)d_in[2];
    const float* ev = (const float*)d_in[3];
    const float* W0 = (const float*)d_in[4];
    const float* W1 = (const float*)d_in[5];
    // d_in[6] = W2: dead in eval path.
    float* out = (float*)d_out;

    char* ws = (char*)d_ws;
    float* XW0  = (float*)(ws);                          // 1 MB
    float* hacc = (float*)(ws + (1 << 20));              // 1 MB
    float* mean = (float*)(ws + (2 << 20));              // 512 KB
    float* HW1  = (float*)(ws + (2 << 20) + (512 << 10));// 512 KB

    // zero the two atomic accumulators (contiguous)
    hipMemsetAsync(hacc, 0, (1 << 20) + (512 << 10), stream);

    k_xw0   <<<NN * H1 / 256, 256, 0, stream>>>(X, W0, XW0);
    k_spmm1 <<<NE * H1 / 256, 256, 0, stream>>>(er, ec, ev, XW0, hacc);
    k_hw1   <<<NN * H2 / 256, 256, 0, stream>>>(hacc, W1, HW1);
    k_spmm2 <<<NE * H2 / 256, 256, 0, stream>>>(er, ec, ev, HW1, mean);
    k_decode<<<dim3(NN / TI, NN / TI), 256, 0, stream>>>(mean, out);
}